// Round 5
// baseline (420.897 us; speedup 1.0000x reference)
//
#include <hip/hip_runtime.h>
#include <hip/hip_bf16.h>
#include <math.h>

#define B 128
#define C 128
#define HW 4096   // 64*64
#define K_TOP 6

// native clang vector type — accepted by __builtin_nontemporal_load/store
typedef float vfloat4 __attribute__((ext_vector_type(4)));

// ---------------------------------------------------------------------------
// Kernel A: ONE WAVE per (b,c) slice (4 waves / 256-thread block).
// Each lane owns 16 float4 (64 floats). Streams the slice with 16 outstanding
// nontemporal loads, streams 16 zero float4 stores (independent), then does a
// pure in-wave shuffle argmax reduce — no LDS, no __syncthreads, no serial
// tail. Tie-break: lowest flat index wins (jnp.argmax first-max semantics).
// pooled/pidx stored transposed [C][B] so kernel B reads coalesced.
// ---------------------------------------------------------------------------
__global__ __launch_bounds__(256) void pool_zero_kernel(
        const float* __restrict__ act,
        float* __restrict__ out,
        float* __restrict__ pooledT,
        int* __restrict__ pidxT) {
    const int wid  = (blockIdx.x << 2) | (threadIdx.x >> 6);  // slice id = b*C+c
    const int lane = threadIdx.x & 63;
    const size_t base = (size_t)wid * HW;
    const vfloat4* __restrict__ src = (const vfloat4*)(act + base);
    vfloat4* __restrict__ dst = (vfloat4*)(out + base);

    // 1) issue all 16 loads (dependent consumers come last -> max MLP)
    vfloat4 v[16];
#pragma unroll
    for (int r = 0; r < 16; ++r)
        v[r] = __builtin_nontemporal_load(&src[lane + (r << 6)]);

    // 2) issue the independent zero-fill stream
    const vfloat4 zero = (vfloat4)(0.f);
#pragma unroll
    for (int r = 0; r < 16; ++r)
        __builtin_nontemporal_store(zero, &dst[lane + (r << 6)]);

    // 3) per-lane scan, increasing flat index -> strict > keeps first max
    float best = -INFINITY;
    int bestIdx = 0;
#pragma unroll
    for (int r = 0; r < 16; ++r) {
        const int ei = (lane + (r << 6)) << 2;   // element index of v[r].x
        if (v[r].x > best) { best = v[r].x; bestIdx = ei;     }
        if (v[r].y > best) { best = v[r].y; bestIdx = ei + 1; }
        if (v[r].z > best) { best = v[r].z; bestIdx = ei + 2; }
        if (v[r].w > best) { best = v[r].w; bestIdx = ei + 3; }
    }

    // 4) wave (64-lane) reduction with lowest-index tie-break
#pragma unroll
    for (int off = 32; off >= 1; off >>= 1) {
        const float ov = __shfl_down(best, off);
        const int   oi = __shfl_down(bestIdx, off);
        if (ov > best || (ov == best && oi < bestIdx)) { best = ov; bestIdx = oi; }
    }

    if (lane == 0) {
        const int b = wid / C;
        const int c = wid % C;
        pooledT[(size_t)c * B + b] = best;   // transposed: [C][B]
        pidxT[(size_t)c * B + b]   = bestIdx;
    }
}

// ---------------------------------------------------------------------------
// Kernel B: one wave per feature c. Iteratively extract the top-6 pooled
// values over the batch dim (lowest-batch-index tie-break, matching
// jax.lax.top_k stable tie order) and scatter them into the zeroed output.
// pooledT/pidxT are [C][B] so the 128-value row is contiguous.
// ---------------------------------------------------------------------------
__global__ __launch_bounds__(64) void topk_scatter_kernel(
        const float* __restrict__ pooledT,
        const int* __restrict__ pidxT,
        float* __restrict__ out) {
    const int c = blockIdx.x;
    const int lane = threadIdx.x;
    const float* row = pooledT + (size_t)c * B;

    // each lane holds two batch candidates: lane and lane+64
    float v0 = row[lane];
    float v1 = row[lane + 64];
    const int b0 = lane;
    const int b1 = lane + 64;

    for (int k = 0; k < K_TOP; ++k) {
        // per-lane best; b0 < b1 so >= prefers lower batch on tie
        float mv; int mb;
        if (v0 >= v1) { mv = v0; mb = b0; } else { mv = v1; mb = b1; }

        float rv = mv; int rb = mb;
#pragma unroll
        for (int off = 32; off >= 1; off >>= 1) {
            const float ov = __shfl_down(rv, off);
            const int   ob = __shfl_down(rb, off);
            if (ov > rv || (ov == rv && ob < rb)) { rv = ov; rb = ob; }
        }
        rv = __shfl(rv, 0);
        rb = __shfl(rb, 0);

        if (lane == 0) {
            const int hw = pidxT[(size_t)c * B + rb];
            out[(size_t)rb * (C * HW) + (size_t)c * HW + (size_t)hw] = rv;
        }

        // invalidate the selected candidate
        if (rb == b0) v0 = -INFINITY;
        else if (rb == b1) v1 = -INFINITY;
    }
}

extern "C" void kernel_launch(void* const* d_in, const int* in_sizes, int n_in,
                              void* d_out, int out_size, void* d_ws, size_t ws_size,
                              hipStream_t stream) {
    const float* act = (const float*)d_in[0];
    float* out = (float*)d_out;

    // workspace: pooledT[C*B] floats + pidxT[C*B] ints = 128 KiB
    float* pooledT = (float*)d_ws;
    int*   pidxT   = (int*)(pooledT + B * C);

    pool_zero_kernel<<<(B * C) / 4, 256, 0, stream>>>(act, out, pooledT, pidxT);
    topk_scatter_kernel<<<C, 64, 0, stream>>>(pooledT, pidxT, out);
}